// Round 4
// baseline (40606.726 us; speedup 1.0000x reference)
//
#include <hip/hip_runtime.h>
#include <hip/hip_bf16.h>

using bf16 = __hip_bfloat16;
using short8 = __attribute__((ext_vector_type(8))) short;
using f32x4 = __attribute__((ext_vector_type(4))) float;

#define BB 512
#define HH 1024
#define DD 64
#define TT 96
#define NBLK 256

__device__ __forceinline__ void load_lds16(const void* g, void* l) {
  __builtin_amdgcn_global_load_lds(
      (const __attribute__((address_space(1))) unsigned int*)g,
      (__attribute__((address_space(3))) unsigned int*)l, 16, 0, 0);
}

__device__ __forceinline__ float sigm(float x) { return 1.0f / (1.0f + __expf(-x)); }
__device__ __forceinline__ float tanh_f(float x) {
  float e = __expf(2.0f * x);
  return 1.0f - 2.0f / (e + 1.0f);
}
__device__ __forceinline__ float wred(float v) {
#pragma unroll
  for (int m = 1; m < 64; m <<= 1) v += __shfl_xor(v, m, 64);
  return v;
}

// gate-row permutation: col c (= g*1024 + n) -> pr = (n>>4)*64 + g*16 + (n&15)
// => every 64-col group is [i16|f16|g16|o16] for 16 consecutive units.
__device__ __forceinline__ int gate_perm(int c) {
  int g = c >> 10, n = c & 1023;
  return (n >> 4) * 64 + g * 16 + (n & 15);
}

// ---------------- preprocessing kernels ----------------

__global__ __launch_bounds__(256) void init_states_k(
    const float* __restrict__ x0, const float* __restrict__ hn, const float* __restrict__ cn,
    bf16* __restrict__ xbh, bf16* __restrict__ xbl,
    bf16* __restrict__ h0h, bf16* __restrict__ h0l,
    bf16* __restrict__ h1h, bf16* __restrict__ h1l,
    float* __restrict__ c0, float* __restrict__ c1, unsigned* __restrict__ barp)
{
  int i = blockIdx.x * 256 + threadIdx.x;
  if (blockIdx.x == 0 && threadIdx.x < 128) barp[threadIdx.x] = 0u;
  if (i < BB * HH) {
    float v0 = hn[i];
    bf16 a0 = __float2bfloat16(v0);
    h0h[i] = a0; h0l[i] = __float2bfloat16(v0 - __bfloat162float(a0));
    float v1 = hn[BB * HH + i];
    bf16 a1 = __float2bfloat16(v1);
    h1h[i] = a1; h1l[i] = __float2bfloat16(v1 - __bfloat162float(a1));
    c0[i] = cn[i];
    c1[i] = cn[BB * HH + i];
  }
  if (i < BB * DD) {
    float v = x0[i];
    bf16 a = __float2bfloat16(v);
    xbh[i] = a; xbl[i] = __float2bfloat16(v - __bfloat162float(a));
  }
}

__global__ __launch_bounds__(256) void fold_emb_k(
    const float* __restrict__ embW, const float* __restrict__ embB,
    const float* __restrict__ Wih0, const float* __restrict__ bih0, const float* __restrict__ bhh0,
    bf16* __restrict__ W0h, bf16* __restrict__ W0l, float* __restrict__ bias0)
{
  __shared__ float sW[512 * 8];
  __shared__ float sb[512];
  int tid = threadIdx.x;
  int d0 = blockIdx.y * 8;
  for (int i = tid; i < 4096; i += 256) {
    int j = i >> 9;
    int e = i & 511;
    sW[e * 8 + j] = embW[(size_t)(d0 + j) * 512 + e];
  }
  for (int i = tid; i < 512; i += 256) sb[i] = embB[i];
  __syncthreads();
  int c = blockIdx.x * 256 + tid;  // 0..4095
  float acc[8] = {0, 0, 0, 0, 0, 0, 0, 0};
  float bacc = 0.0f;
  for (int e = 0; e < 512; ++e) {
    float wv = Wih0[(size_t)e * 4096 + c];
    float4 wa = *(const float4*)&sW[e * 8];
    float4 wb = *(const float4*)&sW[e * 8 + 4];
    acc[0] += wa.x * wv; acc[1] += wa.y * wv; acc[2] += wa.z * wv; acc[3] += wa.w * wv;
    acc[4] += wb.x * wv; acc[5] += wb.y * wv; acc[6] += wb.z * wv; acc[7] += wb.w * wv;
    bacc += sb[e] * wv;
  }
  int pr = gate_perm(c);
#pragma unroll
  for (int j = 0; j < 8; ++j) {
    float v = acc[j];
    bf16 h = __float2bfloat16(v);
    W0h[(size_t)pr * 1088 + d0 + j] = h;
    W0l[(size_t)pr * 1088 + d0 + j] = __float2bfloat16(v - __bfloat162float(h));
  }
  if (blockIdx.y == 0) bias0[pr] = bacc + bih0[c] + bhh0[c];
}

template <bool PERM>
__global__ __launch_bounds__(256) void transpose_conv_k(
    const float* __restrict__ src, int N,
    bf16* __restrict__ dsth, bf16* __restrict__ dstl, int dstStride, int k0)
{
  __shared__ float tb[32][33];
  int tx = threadIdx.x & 31;
  int ty = threadIdx.x >> 5;  // 0..7
  int c0 = blockIdx.x * 32;
  int kk0 = blockIdx.y * 32;
#pragma unroll
  for (int q = 0; q < 4; ++q) {
    int k = kk0 + q * 8 + ty;
    tb[q * 8 + ty][tx] = src[(size_t)k * N + c0 + tx];
  }
  __syncthreads();
#pragma unroll
  for (int q = 0; q < 4; ++q) {
    int cc = c0 + q * 8 + ty;
    int pr = PERM ? gate_perm(cc) : cc;
    float v = tb[tx][q * 8 + ty];
    bf16 h = __float2bfloat16(v);
    size_t di = (size_t)pr * dstStride + k0 + kk0 + tx;
    dsth[di] = h;
    dstl[di] = __float2bfloat16(v - __bfloat162float(h));
  }
}

__global__ __launch_bounds__(256) void bias_perm_k(
    const float* __restrict__ a, const float* __restrict__ b, float* __restrict__ out)
{
  int c = blockIdx.x * 256 + threadIdx.x;
  out[gate_perm(c)] = a[c] + b[c];
}

// ---------------- persistent kernel ----------------

struct PA {
  bf16 *xbh, *xbl;
  bf16 *h0h_a, *h0h_b, *h0l_a, *h0l_b;
  bf16 *h1h_a, *h1h_b, *h1l_a, *h1l_b;
  float *c0, *c1, *z;
  const bf16 *W0h, *W0l, *W1h, *W1l, *F1h, *F1l;
  const float *bias0, *bias1, *fc1b, *lng, *lnb, *W2, *b2;
  float *out;
  unsigned *bar;   // bar[0] = counter, bar[64] = generation
};

__device__ __forceinline__ void gbar(unsigned* bar, int tid) {
  __syncthreads();
  if (tid == 0) {
    __threadfence();
    unsigned* gen = bar + 64;
    unsigned g = __hip_atomic_load(gen, __ATOMIC_RELAXED, __HIP_MEMORY_SCOPE_AGENT);
    unsigned a = __hip_atomic_fetch_add(bar, 1u, __ATOMIC_ACQ_REL, __HIP_MEMORY_SCOPE_AGENT);
    if (a == NBLK - 1) {
      __hip_atomic_store(bar, 0u, __ATOMIC_RELAXED, __HIP_MEMORY_SCOPE_AGENT);
      __hip_atomic_store(gen, g + 1u, __ATOMIC_RELEASE, __HIP_MEMORY_SCOPE_AGENT);
    } else {
      while (__hip_atomic_load(gen, __ATOMIC_ACQUIRE, __HIP_MEMORY_SCOPE_AGENT) == g)
        __builtin_amdgcn_s_sleep(2);
    }
  }
  __syncthreads();
}

// gates GEMM phase: block tile 64m x 128n, 2 waves split-N (wave tile 64x64),
// BK=32 double-buffered (2 x 24KB). acc += Ah*Bh + Ah*Bl + Al*Bh.
// Epilogue: 64-col wave half-panel = [i16|f16|g16|o16] x 16 units -> LSTM cell.
__device__ __forceinline__ void gates_phase(
    char* smem, int bid, int tid,
    const bf16* A1h, const bf16* A1l, int lda1, int K1len,
    const bf16* A2h, const bf16* A2l, int lda2,
    const bf16* Bh, const bf16* Bl, int KTOT,
    const float* bias, float* cst, bf16* hho, bf16* hlo)
{
  const int lane = tid & 63, wv = tid >> 6;
  const int npanel = bid & 31, m0 = (bid >> 5) * 64;
  const int nrow0 = npanel * 128;
  const int l15 = lane & 15, lhi = lane >> 4, kb = lhi * 16;

  f32x4 acc[16];
#pragma unroll
  for (int i = 0; i < 16; ++i) acc[i] = f32x4{0, 0, 0, 0};

  const int ntiles = KTOT >> 5;

  auto stage = [&](int buf, int kt) {
    char* lb = smem + buf * 24576;
    bool first = kt < K1len;
#pragma unroll
    for (int q = 0; q < 2; ++q) {  // A: 64 rows x 4 x 16B
      int L = q * 128 + tid;
      int row = L >> 2, sl = L & 3;
      int sb = (sl * 16) ^ (((row >> 2) & 3) << 4);
      int ke = kt + (sb >> 1);
      const bf16* gh = first ? A1h + (size_t)(m0 + row) * lda1 + ke
                             : A2h + (size_t)(m0 + row) * lda2 + (ke - K1len);
      const bf16* gl = first ? A1l + (size_t)(m0 + row) * lda1 + ke
                             : A2l + (size_t)(m0 + row) * lda2 + (ke - K1len);
      load_lds16(gh, lb + L * 16);
      load_lds16(gl, lb + 4096 + L * 16);
    }
#pragma unroll
    for (int q = 0; q < 4; ++q) {  // B: 128 rows x 4 x 16B
      int L = q * 128 + tid;
      int row = L >> 2, sl = L & 3;
      int sb = (sl * 16) ^ (((row >> 2) & 3) << 4);
      int ke = kt + (sb >> 1);
      load_lds16(Bh + (size_t)(nrow0 + row) * KTOT + ke, lb + 8192 + L * 16);
      load_lds16(Bl + (size_t)(nrow0 + row) * KTOT + ke, lb + 16384 + L * 16);
    }
  };

  stage(0, 0);
  __syncthreads();
  for (int t = 0; t < ntiles; ++t) {
    int cur = t & 1;
    if (t + 1 < ntiles) stage(cur ^ 1, (t + 1) << 5);
    const char* base = smem + cur * 24576;
    short8 ah[4], al[4], bh[4], bl[4];
#pragma unroll
    for (int mf = 0; mf < 4; ++mf) {
      int arow = mf * 16 + l15;
      int aoff = arow * 64 + (kb ^ (((arow >> 2) & 3) << 4));
      ah[mf] = *(const short8*)(base + aoff);
      al[mf] = *(const short8*)(base + 4096 + aoff);
    }
#pragma unroll
    for (int nf = 0; nf < 4; ++nf) {
      int brow = wv * 64 + nf * 16 + l15;
      int boff = brow * 64 + (kb ^ (((brow >> 2) & 3) << 4));
      bh[nf] = *(const short8*)(base + 8192 + boff);
      bl[nf] = *(const short8*)(base + 16384 + boff);
    }
#pragma unroll
    for (int mf = 0; mf < 4; ++mf)
#pragma unroll
      for (int nf = 0; nf < 4; ++nf) {
        f32x4 c = acc[mf * 4 + nf];
        c = __builtin_amdgcn_mfma_f32_16x16x32_bf16(ah[mf], bh[nf], c, 0, 0, 0);
        c = __builtin_amdgcn_mfma_f32_16x16x32_bf16(ah[mf], bl[nf], c, 0, 0, 0);
        c = __builtin_amdgcn_mfma_f32_16x16x32_bf16(al[mf], bh[nf], c, 0, 0, 0);
        acc[mf * 4 + nf] = c;
      }
    __syncthreads();
  }

  const int unit = npanel * 32 + wv * 16 + l15;
  const int prb = npanel * 128 + wv * 64 + l15;
  float bi = bias[prb + 0];
  float bfv = bias[prb + 16];
  float bg = bias[prb + 32];
  float bo = bias[prb + 48];
#pragma unroll
  for (int mf = 0; mf < 4; ++mf) {
    f32x4 ai = acc[mf * 4 + 0], af = acc[mf * 4 + 1];
    f32x4 ag = acc[mf * 4 + 2], ao = acc[mf * 4 + 3];
#pragma unroll
    for (int r = 0; r < 4; ++r) {
      int row = m0 + mf * 16 + lhi * 4 + r;
      size_t idx = (size_t)row * HH + unit;
      float iv = ai[r] + bi, fv = af[r] + bfv, gv = ag[r] + bg, ov = ao[r] + bo;
      float co = cst[idx];
      float cn2 = sigm(fv) * co + sigm(iv) * tanh_f(gv);
      cst[idx] = cn2;
      float hv = sigm(ov) * tanh_f(cn2);
      bf16 hh = __float2bfloat16(hv);
      hho[idx] = hh;
      hlo[idx] = __float2bfloat16(hv - __bfloat162float(hh));
    }
  }
}

// fc1 phase: block tile 32m x 64n, 2 waves split-N (wave 32x32), BK=32 dbuf (2x12KB).
__device__ __forceinline__ void fc1_phase(
    char* smem, int bid, int tid,
    const bf16* Ah, const bf16* Al,
    const bf16* Bh, const bf16* Bl,
    const float* bias, float* z)
{
  const int lane = tid & 63, wv = tid >> 6;
  const int n0 = (bid & 15) * 64, m0 = (bid >> 4) * 32;
  const int l15 = lane & 15, lhi = lane >> 4, kb = lhi * 16;
  f32x4 acc[4];
#pragma unroll
  for (int i = 0; i < 4; ++i) acc[i] = f32x4{0, 0, 0, 0};

  auto stage = [&](int buf, int kt) {
    char* lb = smem + buf * 12288;
    {
      int row = tid >> 2, sl = tid & 3;  // A: 32 rows
      int sb = (sl * 16) ^ (((row >> 2) & 3) << 4);
      int ke = kt + (sb >> 1);
      load_lds16(Ah + (size_t)(m0 + row) * HH + ke, lb + tid * 16);
      load_lds16(Al + (size_t)(m0 + row) * HH + ke, lb + 2048 + tid * 16);
    }
#pragma unroll
    for (int q = 0; q < 2; ++q) {  // B: 64 rows
      int L = q * 128 + tid;
      int row = L >> 2, sl = L & 3;
      int sb = (sl * 16) ^ (((row >> 2) & 3) << 4);
      int ke = kt + (sb >> 1);
      load_lds16(Bh + (size_t)(n0 + row) * HH + ke, lb + 4096 + L * 16);
      load_lds16(Bl + (size_t)(n0 + row) * HH + ke, lb + 8192 + L * 16);
    }
  };
  stage(0, 0);
  __syncthreads();
  for (int t = 0; t < 32; ++t) {
    int cur = t & 1;
    if (t + 1 < 32) stage(cur ^ 1, (t + 1) << 5);
    const char* base = smem + cur * 12288;
    short8 ah[2], al[2], bh[2], bl[2];
#pragma unroll
    for (int mf = 0; mf < 2; ++mf) {
      int arow = mf * 16 + l15;
      int aoff = arow * 64 + (kb ^ (((arow >> 2) & 3) << 4));
      ah[mf] = *(const short8*)(base + aoff);
      al[mf] = *(const short8*)(base + 2048 + aoff);
    }
#pragma unroll
    for (int nf = 0; nf < 2; ++nf) {
      int brow = wv * 32 + nf * 16 + l15;
      int boff = brow * 64 + (kb ^ (((brow >> 2) & 3) << 4));
      bh[nf] = *(const short8*)(base + 4096 + boff);
      bl[nf] = *(const short8*)(base + 8192 + boff);
    }
#pragma unroll
    for (int mf = 0; mf < 2; ++mf)
#pragma unroll
      for (int nf = 0; nf < 2; ++nf) {
        f32x4 c = acc[mf * 2 + nf];
        c = __builtin_amdgcn_mfma_f32_16x16x32_bf16(ah[mf], bh[nf], c, 0, 0, 0);
        c = __builtin_amdgcn_mfma_f32_16x16x32_bf16(ah[mf], bl[nf], c, 0, 0, 0);
        c = __builtin_amdgcn_mfma_f32_16x16x32_bf16(al[mf], bh[nf], c, 0, 0, 0);
        acc[mf * 2 + nf] = c;
      }
    __syncthreads();
  }
#pragma unroll
  for (int mf = 0; mf < 2; ++mf)
#pragma unroll
    for (int nf = 0; nf < 2; ++nf) {
      int col = n0 + wv * 32 + nf * 16 + l15;
      float bb = bias[col];
#pragma unroll
      for (int r = 0; r < 4; ++r) {
        int row = m0 + mf * 16 + lhi * 4 + r;
        z[(size_t)row * HH + col] = acc[mf * 2 + nf][r] + bb;
      }
    }
}

// LN + ReLU + fc2 + out + feedback: 2 rows per block, one wave per row.
__device__ __forceinline__ void ln_phase(
    char* smem, int bid, int tid,
    const float* z, const float* lng, const float* lnb,
    const float* W2, const float* b2,
    float* out, bf16* xbh, bf16* xbl, int tstep)
{
  float* sa = (float*)smem;  // [2][1024]
  const int lane = tid & 63, wv = tid >> 6;
  const int row = bid * 2 + wv;
  float zv[16];
#pragma unroll
  for (int j = 0; j < 16; ++j) zv[j] = z[(size_t)row * HH + j * 64 + lane];
  float s = 0;
#pragma unroll
  for (int j = 0; j < 16; ++j) s += zv[j];
  s = wred(s);
  float mu = s * (1.0f / 1024.0f);
  float vs = 0;
#pragma unroll
  for (int j = 0; j < 16; ++j) { float d = zv[j] - mu; vs += d * d; }
  vs = wred(vs);
  float rstd = rsqrtf(vs * (1.0f / 1024.0f) + 1e-5f);
#pragma unroll
  for (int j = 0; j < 16; ++j) {
    int k = j * 64 + lane;
    float a2 = (zv[j] - mu) * rstd * lng[k] + lnb[k];
    sa[wv * 1024 + k] = a2 > 0.0f ? a2 : 0.0f;
  }
  __syncthreads();
  float y = b2[lane];
#pragma unroll 8
  for (int k = 0; k < 1024; ++k)
    y += sa[wv * 1024 + k] * W2[(size_t)k * DD + lane];
  out[((size_t)row * TT + tstep) * DD + lane] = y;
  bf16 hh = __float2bfloat16(y);
  xbh[(size_t)row * DD + lane] = hh;
  xbl[(size_t)row * DD + lane] = __float2bfloat16(y - __bfloat162float(hh));
}

__global__ __launch_bounds__(128) void persistent_k(PA a)
{
  __shared__ __align__(16) char smem[49152];
  const int tid = threadIdx.x, bid = blockIdx.x;
  bf16 *h0hp = a.h0h_a, *h0hc = a.h0h_b, *h0lp = a.h0l_a, *h0lc = a.h0l_b;
  bf16 *h1hp = a.h1h_a, *h1hc = a.h1h_b, *h1lp = a.h1l_a, *h1lc = a.h1l_b;
  for (int t = 0; t < TT; ++t) {
    gates_phase(smem, bid, tid, a.xbh, a.xbl, DD, DD, h0hp, h0lp, HH,
                a.W0h, a.W0l, 1088, a.bias0, a.c0, h0hc, h0lc);
    gbar(a.bar, tid);
    gates_phase(smem, bid, tid, h0hc, h0lc, HH, HH, h1hp, h1lp, HH,
                a.W1h, a.W1l, 2048, a.bias1, a.c1, h1hc, h1lc);
    gbar(a.bar, tid);
    fc1_phase(smem, bid, tid, h1hc, h1lc, a.F1h, a.F1l, a.fc1b, a.z);
    gbar(a.bar, tid);
    ln_phase(smem, bid, tid, a.z, a.lng, a.lnb, a.W2, a.b2, a.out, a.xbh, a.xbl, t);
    gbar(a.bar, tid);
    bf16* tmp;
    tmp = h0hp; h0hp = h0hc; h0hc = tmp;
    tmp = h0lp; h0lp = h0lc; h0lc = tmp;
    tmp = h1hp; h1hp = h1hc; h1hc = tmp;
    tmp = h1lp; h1lp = h1lc; h1lc = tmp;
  }
}

// ---------------- host ----------------

extern "C" void kernel_launch(void* const* d_in, const int* in_sizes, int n_in,
                              void* d_out, int out_size, void* d_ws, size_t ws_size,
                              hipStream_t stream)
{
  const float* x0   = (const float*)d_in[0];
  const float* hn   = (const float*)d_in[1];
  const float* cn   = (const float*)d_in[2];
  const float* embW = (const float*)d_in[4];
  const float* embB = (const float*)d_in[5];
  const float* Wih0 = (const float*)d_in[6];
  const float* Whh0 = (const float*)d_in[7];
  const float* bih0 = (const float*)d_in[8];
  const float* bhh0 = (const float*)d_in[9];
  const float* Wih1 = (const float*)d_in[10];
  const float* Whh1 = (const float*)d_in[11];
  const float* bih1 = (const float*)d_in[12];
  const float* bhh1 = (const float*)d_in[13];
  const float* fc1W = (const float*)d_in[14];
  const float* fc1b = (const float*)d_in[15];
  const float* lng  = (const float*)d_in[16];
  const float* lnb  = (const float*)d_in[17];
  const float* fc2W = (const float*)d_in[18];
  const float* fc2b = (const float*)d_in[19];

  char* wp = (char*)d_ws;
  size_t off = 0;
  auto alloc = [&](size_t bytes) -> void* {
    void* p = wp + off;
    off += (bytes + 255) & ~(size_t)255;
    return p;
  };

  bf16* W0th  = (bf16*)alloc((size_t)4096 * 1088 * 2);
  bf16* W0tl  = (bf16*)alloc((size_t)4096 * 1088 * 2);
  bf16* W1th  = (bf16*)alloc((size_t)4096 * 2048 * 2);
  bf16* W1tl  = (bf16*)alloc((size_t)4096 * 2048 * 2);
  bf16* f1h   = (bf16*)alloc((size_t)1024 * 1024 * 2);
  bf16* f1l   = (bf16*)alloc((size_t)1024 * 1024 * 2);
  float* bias0 = (float*)alloc(4096 * 4);
  float* bias1 = (float*)alloc(4096 * 4);
  bf16* xbh   = (bf16*)alloc((size_t)BB * DD * 2);
  bf16* xbl   = (bf16*)alloc((size_t)BB * DD * 2);
  bf16* h0h_a = (bf16*)alloc((size_t)BB * HH * 2);
  bf16* h0h_b = (bf16*)alloc((size_t)BB * HH * 2);
  bf16* h0l_a = (bf16*)alloc((size_t)BB * HH * 2);
  bf16* h0l_b = (bf16*)alloc((size_t)BB * HH * 2);
  bf16* h1h_a = (bf16*)alloc((size_t)BB * HH * 2);
  bf16* h1h_b = (bf16*)alloc((size_t)BB * HH * 2);
  bf16* h1l_a = (bf16*)alloc((size_t)BB * HH * 2);
  bf16* h1l_b = (bf16*)alloc((size_t)BB * HH * 2);
  float* c0   = (float*)alloc((size_t)BB * HH * 4);
  float* c1   = (float*)alloc((size_t)BB * HH * 4);
  float* z    = (float*)alloc((size_t)BB * HH * 4);
  unsigned* bar = (unsigned*)alloc(512);

  init_states_k<<<2048, 256, 0, stream>>>(x0, hn, cn, xbh, xbl, h0h_a, h0l_a,
                                          h1h_a, h1l_a, c0, c1, bar);
  fold_emb_k<<<dim3(16, 8), 256, 0, stream>>>(embW, embB, Wih0, bih0, bhh0, W0th, W0tl, bias0);
  transpose_conv_k<true><<<dim3(128, 32), 256, 0, stream>>>(Whh0, 4096, W0th, W0tl, 1088, 64);
  transpose_conv_k<true><<<dim3(128, 32), 256, 0, stream>>>(Wih1, 4096, W1th, W1tl, 2048, 0);
  transpose_conv_k<true><<<dim3(128, 32), 256, 0, stream>>>(Whh1, 4096, W1th, W1tl, 2048, 1024);
  transpose_conv_k<false><<<dim3(32, 32), 256, 0, stream>>>(fc1W, 1024, f1h, f1l, 1024, 0);
  bias_perm_k<<<16, 256, 0, stream>>>(bih1, bhh1, bias1);

  PA pa;
  pa.xbh = xbh; pa.xbl = xbl;
  pa.h0h_a = h0h_a; pa.h0h_b = h0h_b; pa.h0l_a = h0l_a; pa.h0l_b = h0l_b;
  pa.h1h_a = h1h_a; pa.h1h_b = h1h_b; pa.h1l_a = h1l_a; pa.h1l_b = h1l_b;
  pa.c0 = c0; pa.c1 = c1; pa.z = z;
  pa.W0h = W0th; pa.W0l = W0tl; pa.W1h = W1th; pa.W1l = W1tl;
  pa.F1h = f1h; pa.F1l = f1l;
  pa.bias0 = bias0; pa.bias1 = bias1; pa.fc1b = fc1b;
  pa.lng = lng; pa.lnb = lnb; pa.W2 = fc2W; pa.b2 = fc2b;
  pa.out = (float*)d_out;
  pa.bar = bar;

  persistent_k<<<NBLK, 128, 0, stream>>>(pa);
}

// Round 5
// 11517.656 us; speedup vs baseline: 3.5256x; 3.5256x over previous
//
#include <hip/hip_runtime.h>
#include <hip/hip_bf16.h>

using bf16 = __hip_bfloat16;
using short8 = __attribute__((ext_vector_type(8))) short;
using f32x4 = __attribute__((ext_vector_type(4))) float;

#define BB 512
#define HH 1024
#define DD 64
#define TT 96

__device__ __forceinline__ void load_lds16(const void* g, void* l) {
  __builtin_amdgcn_global_load_lds(
      (const __attribute__((address_space(1))) unsigned int*)g,
      (__attribute__((address_space(3))) unsigned int*)l, 16, 0, 0);
}

__device__ __forceinline__ float sigm(float x) { return 1.0f / (1.0f + __expf(-x)); }
__device__ __forceinline__ float tanh_f(float x) {
  float e = __expf(2.0f * x);
  return 1.0f - 2.0f / (e + 1.0f);
}
__device__ __forceinline__ float wred(float v) {
#pragma unroll
  for (int m = 1; m < 64; m <<= 1) v += __shfl_xor(v, m, 64);
  return v;
}

// gate-row permutation: col c (= g*1024 + n) -> pr = (n>>4)*64 + g*16 + (n&15)
// => every 64-col group is [i16|f16|g16|o16] for 16 consecutive units.
__device__ __forceinline__ int gate_perm(int c) {
  int g = c >> 10, n = c & 1023;
  return (n >> 4) * 64 + g * 16 + (n & 15);
}

// ---------------- preprocessing kernels ----------------

__global__ __launch_bounds__(256) void init_states_k(
    const float* __restrict__ x0, const float* __restrict__ hn, const float* __restrict__ cn,
    bf16* __restrict__ xbh, bf16* __restrict__ xbl,
    bf16* __restrict__ h0h, bf16* __restrict__ h0l,
    bf16* __restrict__ h1h, bf16* __restrict__ h1l,
    float* __restrict__ c0, float* __restrict__ c1)
{
  int i = blockIdx.x * 256 + threadIdx.x;
  if (i < BB * HH) {
    float v0 = hn[i];
    bf16 a0 = __float2bfloat16(v0);
    h0h[i] = a0; h0l[i] = __float2bfloat16(v0 - __bfloat162float(a0));
    float v1 = hn[BB * HH + i];
    bf16 a1 = __float2bfloat16(v1);
    h1h[i] = a1; h1l[i] = __float2bfloat16(v1 - __bfloat162float(a1));
    c0[i] = cn[i];
    c1[i] = cn[BB * HH + i];
  }
  if (i < BB * DD) {
    float v = x0[i];
    bf16 a = __float2bfloat16(v);
    xbh[i] = a; xbl[i] = __float2bfloat16(v - __bfloat162float(a));
  }
}

__global__ __launch_bounds__(256) void fold_emb_k(
    const float* __restrict__ embW, const float* __restrict__ embB,
    const float* __restrict__ Wih0, const float* __restrict__ bih0, const float* __restrict__ bhh0,
    bf16* __restrict__ W0h, bf16* __restrict__ W0l, float* __restrict__ bias0)
{
  __shared__ float sW[512 * 8];
  __shared__ float sb[512];
  int tid = threadIdx.x;
  int d0 = blockIdx.y * 8;
  for (int i = tid; i < 4096; i += 256) {
    int j = i >> 9;
    int e = i & 511;
    sW[e * 8 + j] = embW[(size_t)(d0 + j) * 512 + e];
  }
  for (int i = tid; i < 512; i += 256) sb[i] = embB[i];
  __syncthreads();
  int c = blockIdx.x * 256 + tid;  // 0..4095
  float acc[8] = {0, 0, 0, 0, 0, 0, 0, 0};
  float bacc = 0.0f;
  for (int e = 0; e < 512; ++e) {
    float wv = Wih0[(size_t)e * 4096 + c];
    float4 wa = *(const float4*)&sW[e * 8];
    float4 wb = *(const float4*)&sW[e * 8 + 4];
    acc[0] += wa.x * wv; acc[1] += wa.y * wv; acc[2] += wa.z * wv; acc[3] += wa.w * wv;
    acc[4] += wb.x * wv; acc[5] += wb.y * wv; acc[6] += wb.z * wv; acc[7] += wb.w * wv;
    bacc += sb[e] * wv;
  }
  int pr = gate_perm(c);
#pragma unroll
  for (int j = 0; j < 8; ++j) {
    float v = acc[j];
    bf16 h = __float2bfloat16(v);
    W0h[(size_t)pr * 1088 + d0 + j] = h;
    W0l[(size_t)pr * 1088 + d0 + j] = __float2bfloat16(v - __bfloat162float(h));
  }
  if (blockIdx.y == 0) bias0[pr] = bacc + bih0[c] + bhh0[c];
}

template <bool PERM>
__global__ __launch_bounds__(256) void transpose_conv_k(
    const float* __restrict__ src, int N,
    bf16* __restrict__ dsth, bf16* __restrict__ dstl, int dstStride, int k0)
{
  __shared__ float tb[32][33];
  int tx = threadIdx.x & 31;
  int ty = threadIdx.x >> 5;  // 0..7
  int c0 = blockIdx.x * 32;
  int kk0 = blockIdx.y * 32;
#pragma unroll
  for (int q = 0; q < 4; ++q) {
    int k = kk0 + q * 8 + ty;
    tb[q * 8 + ty][tx] = src[(size_t)k * N + c0 + tx];
  }
  __syncthreads();
#pragma unroll
  for (int q = 0; q < 4; ++q) {
    int cc = c0 + q * 8 + ty;
    int pr = PERM ? gate_perm(cc) : cc;
    float v = tb[tx][q * 8 + ty];
    bf16 h = __float2bfloat16(v);
    size_t di = (size_t)pr * dstStride + k0 + kk0 + tx;
    dsth[di] = h;
    dstl[di] = __float2bfloat16(v - __bfloat162float(h));
  }
}

__global__ __launch_bounds__(256) void bias_perm_k(
    const float* __restrict__ a, const float* __restrict__ b, float* __restrict__ out)
{
  int c = blockIdx.x * 256 + threadIdx.x;
  out[gate_perm(c)] = a[c] + b[c];
}

// ---------------- pipelined GEMM (+ optional LSTM-cell epilogue) ----------------
// Block tile 64m x 128n, 2 waves split-N (wave tile 64x64), BK=32.
// 4 LDS buffers (4 x 24KB = 96KB), 3-tile lookahead, counted vmcnt (12 loads/stage),
// ONE raw s_barrier per tile (lgkmcnt(0) before it makes 3-ahead staging race-free).
// acc += Ah*Bh + Ah*Bl + Al*Bh.
// EPI==0: 64-col wave half-panel = [i16|f16|g16|o16] x 16 units -> LSTM cell.
// EPI==1: f32 + bias -> zout.
template <int EPI>
__global__ __launch_bounds__(128) void gemm_pipe_k(
    const bf16* __restrict__ A1h, const bf16* __restrict__ A1l, int lda1, int K1len,
    const bf16* __restrict__ A2h, const bf16* __restrict__ A2l, int lda2,
    const bf16* __restrict__ Bh, const bf16* __restrict__ Bl, int KTOT,
    const float* __restrict__ bias,
    float* __restrict__ zout, float* __restrict__ cst,
    bf16* __restrict__ hho, bf16* __restrict__ hlo,
    int nPanels)
{
  __shared__ __align__(16) char smem[98304];  // 4 buffers x (A 8KB | B 16KB)
  const int tid = threadIdx.x, lane = tid & 63, wv = tid >> 6;
  const int bid = blockIdx.x;
  const int npanel = bid % nPanels;      // n fastest -> same B panel on same XCD
  const int m0 = (bid / nPanels) * 64;
  const int nrow0 = npanel * 128;
  const int l15 = lane & 15, lhi = lane >> 4, kb = lhi * 16;

  f32x4 acc[16];
#pragma unroll
  for (int i = 0; i < 16; ++i) acc[i] = f32x4{0, 0, 0, 0};

  const int nt = KTOT >> 5;

  auto stage = [&](int buf, int kt) {   // 12 global_load_lds per wave
    char* lb = smem + buf * 24576;
    bool first = kt < K1len;
#pragma unroll
    for (int q = 0; q < 2; ++q) {  // A: 64 rows x 64B (hi+lo)
      int L = q * 128 + tid;
      int row = L >> 2, sl = L & 3;
      int sb = (sl * 16) ^ (((row >> 2) & 3) << 4);
      int ke = kt + (sb >> 1);
      const bf16* gh = first ? A1h + (size_t)(m0 + row) * lda1 + ke
                             : A2h + (size_t)(m0 + row) * lda2 + (ke - K1len);
      const bf16* gl = first ? A1l + (size_t)(m0 + row) * lda1 + ke
                             : A2l + (size_t)(m0 + row) * lda2 + (ke - K1len);
      load_lds16(gh, lb + L * 16);
      load_lds16(gl, lb + 4096 + L * 16);
    }
#pragma unroll
    for (int q = 0; q < 4; ++q) {  // B: 128 rows x 64B (hi+lo)
      int L = q * 128 + tid;
      int row = L >> 2, sl = L & 3;
      int sb = (sl * 16) ^ (((row >> 2) & 3) << 4);
      int ke = kt + (sb >> 1);
      load_lds16(Bh + (size_t)(nrow0 + row) * KTOT + ke, lb + 8192 + L * 16);
      load_lds16(Bl + (size_t)(nrow0 + row) * KTOT + ke, lb + 16384 + L * 16);
    }
  };

  stage(0, 0);
  if (nt > 1) stage(1, 32);
  if (nt > 2) stage(2, 64);

  for (int t = 0; t < nt; ++t) {
    int ahead = nt - 1 - t;  // staged tiles beyond t (uniform)
    if (ahead >= 2)      asm volatile("s_waitcnt vmcnt(24)" ::: "memory");
    else if (ahead == 1) asm volatile("s_waitcnt vmcnt(12)" ::: "memory");
    else                 asm volatile("s_waitcnt vmcnt(0)"  ::: "memory");
    asm volatile("s_waitcnt lgkmcnt(0)" ::: "memory");
    __builtin_amdgcn_s_barrier();
    __builtin_amdgcn_sched_barrier(0);
    if (t + 3 < nt) stage((t + 3) & 3, (t + 3) << 5);  // overwrites buf[(t-1)&3]: safe
    const char* base = smem + (t & 3) * 24576;
    short8 ah[4], al[4], bh[4], bl[4];
#pragma unroll
    for (int mf = 0; mf < 4; ++mf) {
      int arow = mf * 16 + l15;
      int aoff = arow * 64 + (kb ^ (((arow >> 2) & 3) << 4));
      ah[mf] = *(const short8*)(base + aoff);
      al[mf] = *(const short8*)(base + 4096 + aoff);
    }
#pragma unroll
    for (int nf = 0; nf < 4; ++nf) {
      int brow = wv * 64 + nf * 16 + l15;
      int boff = brow * 64 + (kb ^ (((brow >> 2) & 3) << 4));
      bh[nf] = *(const short8*)(base + 8192 + boff);
      bl[nf] = *(const short8*)(base + 16384 + boff);
    }
#pragma unroll
    for (int mf = 0; mf < 4; ++mf)
#pragma unroll
      for (int nf = 0; nf < 4; ++nf) {
        f32x4 c = acc[mf * 4 + nf];
        c = __builtin_amdgcn_mfma_f32_16x16x32_bf16(ah[mf], bh[nf], c, 0, 0, 0);
        c = __builtin_amdgcn_mfma_f32_16x16x32_bf16(ah[mf], bl[nf], c, 0, 0, 0);
        c = __builtin_amdgcn_mfma_f32_16x16x32_bf16(al[mf], bh[nf], c, 0, 0, 0);
        acc[mf * 4 + nf] = c;
      }
  }

  if (EPI == 0) {
    const int unit = npanel * 32 + wv * 16 + l15;
    const int prb = npanel * 128 + wv * 64 + l15;
    float bi = bias[prb + 0];
    float bfv = bias[prb + 16];
    float bg = bias[prb + 32];
    float bo = bias[prb + 48];
#pragma unroll
    for (int mf = 0; mf < 4; ++mf) {
      f32x4 ai = acc[mf * 4 + 0], af = acc[mf * 4 + 1];
      f32x4 ag = acc[mf * 4 + 2], ao = acc[mf * 4 + 3];
#pragma unroll
      for (int r = 0; r < 4; ++r) {
        int row = m0 + mf * 16 + lhi * 4 + r;
        size_t idx = (size_t)row * HH + unit;
        float iv = ai[r] + bi, fv = af[r] + bfv, gv = ag[r] + bg, ov = ao[r] + bo;
        float co = cst[idx];
        float cn2 = sigm(fv) * co + sigm(iv) * tanh_f(gv);
        cst[idx] = cn2;
        float hv = sigm(ov) * tanh_f(cn2);
        bf16 hh = __float2bfloat16(hv);
        hho[idx] = hh;
        hlo[idx] = __float2bfloat16(hv - __bfloat162float(hh));
      }
    }
  } else {
#pragma unroll
    for (int mf = 0; mf < 4; ++mf)
#pragma unroll
      for (int nf = 0; nf < 4; ++nf) {
        int col = npanel * 128 + wv * 64 + nf * 16 + l15;
        float bb = bias[col];
#pragma unroll
        for (int r = 0; r < 4; ++r) {
          int row = m0 + mf * 16 + lhi * 4 + r;
          zout[(size_t)row * HH + col] = acc[mf * 4 + nf][r] + bb;
        }
      }
  }
}

// ---------------- LayerNorm + ReLU + fc2 (f32) + output + feedback ----------------
__global__ __launch_bounds__(256) void ln_fc2_k(
    const float* __restrict__ z, const float* __restrict__ lng, const float* __restrict__ lnb,
    const float* __restrict__ W2 /*[1024][64]*/, const float* __restrict__ b2,
    float* __restrict__ out /*[512][96][64]*/,
    bf16* __restrict__ xbh, bf16* __restrict__ xbl, int tstep)
{
  __shared__ float sa[4][1024];
  __shared__ float red[4][4][64];
  int tid = threadIdx.x, lane = tid & 63, w = tid >> 6;
  int row = blockIdx.x * 4 + w;
  float zv[16];
#pragma unroll
  for (int j = 0; j < 16; ++j) zv[j] = z[(size_t)row * 1024 + j * 64 + lane];
  float s = 0;
#pragma unroll
  for (int j = 0; j < 16; ++j) s += zv[j];
  s = wred(s);
  float mu = s * (1.0f / 1024.0f);
  float vs = 0;
#pragma unroll
  for (int j = 0; j < 16; ++j) { float d = zv[j] - mu; vs += d * d; }
  vs = wred(vs);
  float rstd = rsqrtf(vs * (1.0f / 1024.0f) + 1e-5f);
#pragma unroll
  for (int j = 0; j < 16; ++j) {
    int k = j * 64 + lane;
    float a = (zv[j] - mu) * rstd * lng[k] + lnb[k];
    sa[w][k] = a > 0.0f ? a : 0.0f;
  }
  __syncthreads();
  int n = tid & 63, ks = (tid >> 6) * 256;
  float p0 = 0, p1 = 0, p2 = 0, p3 = 0;
  for (int k = ks; k < ks + 256; ++k) {
    float wv2 = W2[(size_t)k * 64 + n];
    p0 += sa[0][k] * wv2; p1 += sa[1][k] * wv2; p2 += sa[2][k] * wv2; p3 += sa[3][k] * wv2;
  }
  int sl = tid >> 6;
  red[0][sl][n] = p0; red[1][sl][n] = p1; red[2][sl][n] = p2; red[3][sl][n] = p3;
  __syncthreads();
  int rr = tid >> 6;
  float y = red[rr][0][n] + red[rr][1][n] + red[rr][2][n] + red[rr][3][n] + b2[n];
  int orow = blockIdx.x * 4 + rr;
  out[((size_t)orow * TT + tstep) * DD + n] = y;
  bf16 hh = __float2bfloat16(y);
  xbh[(size_t)orow * DD + n] = hh;
  xbl[(size_t)orow * DD + n] = __float2bfloat16(y - __bfloat162float(hh));
}

// ---------------- host ----------------

extern "C" void kernel_launch(void* const* d_in, const int* in_sizes, int n_in,
                              void* d_out, int out_size, void* d_ws, size_t ws_size,
                              hipStream_t stream)
{
  const float* x0   = (const float*)d_in[0];
  const float* hn   = (const float*)d_in[1];
  const float* cn   = (const float*)d_in[2];
  const float* embW = (const float*)d_in[4];
  const float* embB = (const float*)d_in[5];
  const float* Wih0 = (const float*)d_in[6];
  const float* Whh0 = (const float*)d_in[7];
  const float* bih0 = (const float*)d_in[8];
  const float* bhh0 = (const float*)d_in[9];
  const float* Wih1 = (const float*)d_in[10];
  const float* Whh1 = (const float*)d_in[11];
  const float* bih1 = (const float*)d_in[12];
  const float* bhh1 = (const float*)d_in[13];
  const float* fc1W = (const float*)d_in[14];
  const float* fc1b = (const float*)d_in[15];
  const float* lng  = (const float*)d_in[16];
  const float* lnb  = (const float*)d_in[17];
  const float* fc2W = (const float*)d_in[18];
  const float* fc2b = (const float*)d_in[19];

  char* wp = (char*)d_ws;
  size_t off = 0;
  auto alloc = [&](size_t bytes) -> void* {
    void* p = wp + off;
    off += (bytes + 255) & ~(size_t)255;
    return p;
  };

  bf16* W0th  = (bf16*)alloc((size_t)4096 * 1088 * 2);
  bf16* W0tl  = (bf16*)alloc((size_t)4096 * 1088 * 2);
  bf16* W1th  = (bf16*)alloc((size_t)4096 * 2048 * 2);
  bf16* W1tl  = (bf16*)alloc((size_t)4096 * 2048 * 2);
  bf16* f1h   = (bf16*)alloc((size_t)1024 * 1024 * 2);
  bf16* f1l   = (bf16*)alloc((size_t)1024 * 1024 * 2);
  float* bias0 = (float*)alloc(4096 * 4);
  float* bias1 = (float*)alloc(4096 * 4);
  bf16* xbh   = (bf16*)alloc((size_t)BB * DD * 2);
  bf16* xbl   = (bf16*)alloc((size_t)BB * DD * 2);
  bf16* h0h_a = (bf16*)alloc((size_t)BB * HH * 2);
  bf16* h0h_b = (bf16*)alloc((size_t)BB * HH * 2);
  bf16* h0l_a = (bf16*)alloc((size_t)BB * HH * 2);
  bf16* h0l_b = (bf16*)alloc((size_t)BB * HH * 2);
  bf16* h1h_a = (bf16*)alloc((size_t)BB * HH * 2);
  bf16* h1h_b = (bf16*)alloc((size_t)BB * HH * 2);
  bf16* h1l_a = (bf16*)alloc((size_t)BB * HH * 2);
  bf16* h1l_b = (bf16*)alloc((size_t)BB * HH * 2);
  float* c0   = (float*)alloc((size_t)BB * HH * 4);
  float* c1   = (float*)alloc((size_t)BB * HH * 4);
  float* z    = (float*)alloc((size_t)BB * HH * 4);

  init_states_k<<<2048, 256, 0, stream>>>(x0, hn, cn, xbh, xbl, h0h_a, h0l_a,
                                          h1h_a, h1l_a, c0, c1);
  fold_emb_k<<<dim3(16, 8), 256, 0, stream>>>(embW, embB, Wih0, bih0, bhh0, W0th, W0tl, bias0);
  transpose_conv_k<true><<<dim3(128, 32), 256, 0, stream>>>(Whh0, 4096, W0th, W0tl, 1088, 64);
  transpose_conv_k<true><<<dim3(128, 32), 256, 0, stream>>>(Wih1, 4096, W1th, W1tl, 2048, 0);
  transpose_conv_k<true><<<dim3(128, 32), 256, 0, stream>>>(Whh1, 4096, W1th, W1tl, 2048, 1024);
  transpose_conv_k<false><<<dim3(32, 32), 256, 0, stream>>>(fc1W, 1024, f1h, f1l, 1024, 0);
  bias_perm_k<<<16, 256, 0, stream>>>(bih1, bhh1, bias1);

  bf16* h0h[2] = {h0h_a, h0h_b};
  bf16* h0l[2] = {h0l_a, h0l_b};
  bf16* h1h[2] = {h1h_a, h1h_b};
  bf16* h1l[2] = {h1l_a, h1l_b};
  float* outp = (float*)d_out;

  for (int t = 0; t < TT; ++t) {
    int p = t & 1;
    // gates0 (+cell0): A = [x | h0_prev], K = 1088; grid 8m x 32n = 256 blocks
    gemm_pipe_k<0><<<256, 128, 0, stream>>>(
        xbh, xbl, DD, DD, h0h[p], h0l[p], HH, W0th, W0tl, 1088, bias0,
        nullptr, c0, h0h[p ^ 1], h0l[p ^ 1], 32);
    // gates1 (+cell1): A = [h0_cur | h1_prev], K = 2048
    gemm_pipe_k<0><<<256, 128, 0, stream>>>(
        h0h[p ^ 1], h0l[p ^ 1], HH, HH, h1h[p], h1l[p], HH, W1th, W1tl, 2048, bias1,
        nullptr, c1, h1h[p ^ 1], h1l[p ^ 1], 32);
    // fc1: z = h1_cur @ fc1W + b, K = 1024; grid 8m x 8n = 64 blocks
    gemm_pipe_k<1><<<64, 128, 0, stream>>>(
        h1h[p ^ 1], h1l[p ^ 1], HH, 1024, h1h[p ^ 1], h1l[p ^ 1], HH, f1h, f1l, 1024,
        fc1b, z, nullptr, nullptr, nullptr, 8);
    // LN + ReLU + fc2 (f32) + write out[:, t, :] + feedback x hi/lo
    ln_fc2_k<<<128, 256, 0, stream>>>(z, lng, lnb, fc2W, fc2b, outp, xbh, xbl, t);
  }
}